// Round 1
// baseline (83.205 us; speedup 1.0000x reference)
//
#include <hip/hip_runtime.h>
#include <cstdint>

#define IN_F 8192
#define OUT_F 8192
#define ROWS 768            // packed rows = IN_F/32*3
#define KCHUNKS 32          // grid.y
#define ROWS_PER_CHUNK 24   // 768/32
#define KB_PER_CHUNK 8      // 24/3 k-blocks (32 in-features each)
#define COLS_PER_BLOCK 256

__global__ __launch_bounds__(256) void q3gemv(
    const float* __restrict__ x, const uint32_t* __restrict__ qw,
    const float* __restrict__ scales, const float* __restrict__ zeros,
    const float* __restrict__ bias, float* __restrict__ out)
{
    __shared__ float x_lds[COLS_PER_BLOCK];
    __shared__ float red[4];

    const int tid = threadIdx.x;
    const int col = blockIdx.x * COLS_PER_BLOCK + tid;
    const int kc  = blockIdx.y;

    // Stage this block's x slice (256 in-features) and block-reduce its sum.
    float xv = x[kc * 256 + tid];
    x_lds[tid] = xv;
    float s = xv;
    #pragma unroll
    for (int off = 32; off > 0; off >>= 1)
        s += __shfl_down(s, off, 64);
    const int wid  = tid >> 6;
    const int lane = tid & 63;
    if (lane == 0) red[wid] = s;
    __syncthreads();
    const float sx_slice = red[0] + red[1] + red[2] + red[3];

    // Each thread: one column, 24 packed rows (8 k-blocks of 3 words).
    const uint32_t* qp = qw + (size_t)(kc * ROWS_PER_CHUNK) * OUT_F + col;
    float a0 = 0.f, a1 = 0.f, a2 = 0.f, a3 = 0.f;

    #pragma unroll
    for (int kb = 0; kb < KB_PER_CHUNK; ++kb) {
        const uint32_t w0 = qp[0];
        const uint32_t w1 = qp[OUT_F];
        const uint32_t w2 = qp[2 * OUT_F];
        qp += 3 * OUT_F;
        const float* xs = &x_lds[kb * 32];

        a0 += xs[0]  * (float)( w0         & 7u);
        a1 += xs[1]  * (float)((w0 >> 3)   & 7u);
        a2 += xs[2]  * (float)((w0 >> 6)   & 7u);
        a3 += xs[3]  * (float)((w0 >> 9)   & 7u);
        a0 += xs[4]  * (float)((w0 >> 12)  & 7u);
        a1 += xs[5]  * (float)((w0 >> 15)  & 7u);
        a2 += xs[6]  * (float)((w0 >> 18)  & 7u);
        a3 += xs[7]  * (float)((w0 >> 21)  & 7u);
        a0 += xs[8]  * (float)((w0 >> 24)  & 7u);
        a1 += xs[9]  * (float)((w0 >> 27)  & 7u);
        a2 += xs[10] * (float)(((w0 >> 30) & 3u) | ((w1 & 1u) << 2));
        a3 += xs[11] * (float)((w1 >> 1)   & 7u);
        a0 += xs[12] * (float)((w1 >> 4)   & 7u);
        a1 += xs[13] * (float)((w1 >> 7)   & 7u);
        a2 += xs[14] * (float)((w1 >> 10)  & 7u);
        a3 += xs[15] * (float)((w1 >> 13)  & 7u);
        a0 += xs[16] * (float)((w1 >> 16)  & 7u);
        a1 += xs[17] * (float)((w1 >> 19)  & 7u);
        a2 += xs[18] * (float)((w1 >> 22)  & 7u);
        a3 += xs[19] * (float)((w1 >> 25)  & 7u);
        a0 += xs[20] * (float)((w1 >> 28)  & 7u);
        a1 += xs[21] * (float)(((w1 >> 31) & 1u) | ((w2 & 3u) << 1));
        a2 += xs[22] * (float)((w2 >> 2)   & 7u);
        a3 += xs[23] * (float)((w2 >> 5)   & 7u);
        a0 += xs[24] * (float)((w2 >> 8)   & 7u);
        a1 += xs[25] * (float)((w2 >> 11)  & 7u);
        a2 += xs[26] * (float)((w2 >> 14)  & 7u);
        a3 += xs[27] * (float)((w2 >> 17)  & 7u);
        a0 += xs[28] * (float)((w2 >> 20)  & 7u);
        a1 += xs[29] * (float)((w2 >> 23)  & 7u);
        a2 += xs[30] * (float)((w2 >> 26)  & 7u);
        a3 += xs[31] * (float)((w2 >> 29)  & 7u);
    }

    const float dot = (a0 + a1) + (a2 + a3);
    float v = scales[col] * dot - zeros[col] * sx_slice;
    if (kc == 0) v += bias[col];
    atomicAdd(&out[col], v);
}

extern "C" void kernel_launch(void* const* d_in, const int* in_sizes, int n_in,
                              void* d_out, int out_size, void* d_ws, size_t ws_size,
                              hipStream_t stream) {
    const float*    x      = (const float*)d_in[0];
    const uint32_t* qw     = (const uint32_t*)d_in[1];
    const float*    scales = (const float*)d_in[2];
    const float*    zeros  = (const float*)d_in[3];
    const float*    bias   = (const float*)d_in[4];
    float* out = (float*)d_out;

    hipMemsetAsync(out, 0, OUT_F * sizeof(float), stream);

    dim3 grid(OUT_F / COLS_PER_BLOCK, KCHUNKS);
    q3gemv<<<grid, 256, 0, stream>>>(x, qw, scales, zeros, bias, out);
}

// Round 2
// 79.686 us; speedup vs baseline: 1.0442x; 1.0442x over previous
//
#include <hip/hip_runtime.h>
#include <cstdint>

#define IN_F 8192
#define OUT_F 8192
#define KCHUNKS 32          // grid.y
#define ROWS_PER_CHUNK 24   // 768/32
#define KB_PER_CHUNK 8      // 24/3 k-blocks (32 in-features each)
#define COLS_PER_BLOCK 256

__global__ __launch_bounds__(256) void q3gemv(
    const float* __restrict__ x, const uint32_t* __restrict__ qw,
    const float* __restrict__ scales, const float* __restrict__ zeros,
    const float* __restrict__ bias, float* __restrict__ out)
{
    __shared__ float red[4];

    const int tid = threadIdx.x;
    const int col = blockIdx.x * COLS_PER_BLOCK + tid;
    const int kc  = blockIdx.y;

    // Block-reduce this chunk's sum of x (for the zeros correction).
    float xv = x[kc * 256 + tid];
    float s = xv;
    #pragma unroll
    for (int off = 32; off > 0; off >>= 1)
        s += __shfl_down(s, off, 64);
    const int wid  = tid >> 6;
    const int lane = tid & 63;
    if (lane == 0) red[wid] = s;
    __syncthreads();
    const float sx_slice = red[0] + red[1] + red[2] + red[3];

    // Each thread: one column, 24 packed rows (8 k-blocks of 3 words).
    // x is read via wave-uniform addresses -> scalar loads (s_load) into SGPRs.
    const uint32_t* qp = qw + (size_t)(kc * ROWS_PER_CHUNK) * OUT_F + col;
    const float* xb = x + kc * 256;
    float a0 = 0.f, a1 = 0.f, a2 = 0.f, a3 = 0.f;

    #pragma unroll
    for (int kb = 0; kb < KB_PER_CHUNK; ++kb) {
        const uint32_t w0 = qp[0];
        const uint32_t w1 = qp[OUT_F];
        const uint32_t w2 = qp[2 * OUT_F];
        qp += 3 * OUT_F;
        const float* xs = xb + kb * 32;   // uniform address

        a0 += xs[0]  * (float)( w0         & 7u);
        a1 += xs[1]  * (float)((w0 >> 3)   & 7u);
        a2 += xs[2]  * (float)((w0 >> 6)   & 7u);
        a3 += xs[3]  * (float)((w0 >> 9)   & 7u);
        a0 += xs[4]  * (float)((w0 >> 12)  & 7u);
        a1 += xs[5]  * (float)((w0 >> 15)  & 7u);
        a2 += xs[6]  * (float)((w0 >> 18)  & 7u);
        a3 += xs[7]  * (float)((w0 >> 21)  & 7u);
        a0 += xs[8]  * (float)((w0 >> 24)  & 7u);
        a1 += xs[9]  * (float)((w0 >> 27)  & 7u);
        a2 += xs[10] * (float)(((w0 >> 30) & 3u) | ((w1 & 1u) << 2));
        a3 += xs[11] * (float)((w1 >> 1)   & 7u);
        a0 += xs[12] * (float)((w1 >> 4)   & 7u);
        a1 += xs[13] * (float)((w1 >> 7)   & 7u);
        a2 += xs[14] * (float)((w1 >> 10)  & 7u);
        a3 += xs[15] * (float)((w1 >> 13)  & 7u);
        a0 += xs[16] * (float)((w1 >> 16)  & 7u);
        a1 += xs[17] * (float)((w1 >> 19)  & 7u);
        a2 += xs[18] * (float)((w1 >> 22)  & 7u);
        a3 += xs[19] * (float)((w1 >> 25)  & 7u);
        a0 += xs[20] * (float)((w1 >> 28)  & 7u);
        a1 += xs[21] * (float)(((w1 >> 31) & 1u) | ((w2 & 3u) << 1));
        a2 += xs[22] * (float)((w2 >> 2)   & 7u);
        a3 += xs[23] * (float)((w2 >> 5)   & 7u);
        a0 += xs[24] * (float)((w2 >> 8)   & 7u);
        a1 += xs[25] * (float)((w2 >> 11)  & 7u);
        a2 += xs[26] * (float)((w2 >> 14)  & 7u);
        a3 += xs[27] * (float)((w2 >> 17)  & 7u);
        a0 += xs[28] * (float)((w2 >> 20)  & 7u);
        a1 += xs[29] * (float)((w2 >> 23)  & 7u);
        a2 += xs[30] * (float)((w2 >> 26)  & 7u);
        a3 += xs[31] * (float)((w2 >> 29)  & 7u);
    }

    const float dot = (a0 + a1) + (a2 + a3);
    float v = scales[col] * dot - zeros[col] * sx_slice;
    if (kc == 0) v += bias[col];
    atomicAdd(&out[col], v);
}

extern "C" void kernel_launch(void* const* d_in, const int* in_sizes, int n_in,
                              void* d_out, int out_size, void* d_ws, size_t ws_size,
                              hipStream_t stream) {
    const float*    x      = (const float*)d_in[0];
    const uint32_t* qw     = (const uint32_t*)d_in[1];
    const float*    scales = (const float*)d_in[2];
    const float*    zeros  = (const float*)d_in[3];
    const float*    bias   = (const float*)d_in[4];
    float* out = (float*)d_out;

    hipMemsetAsync(out, 0, OUT_F * sizeof(float), stream);

    dim3 grid(OUT_F / COLS_PER_BLOCK, KCHUNKS);
    q3gemv<<<grid, 256, 0, stream>>>(x, qw, scales, zeros, bias, out);
}